// Round 5
// baseline (108.917 us; speedup 1.0000x reference)
//
#include <hip/hip_runtime.h>

// ---------------------------------------------------------------------------
// relu-attention block (B=2, Ci=128, Co=64, N=4096):
//   theta/phi/psi = 1x1conv(z); g = phi^T psi; P = relu(g/N);
//   tmp = P theta^T; out = w_v tmp + b_v + z.
// K1 proj: Q(phi/N)[b][n][64], K(psi)[b][n][64], V(theta^T)[b][o][n] bf16
// K2 attn: NO-LDS main loop. 32x32x16 MFMA, swapped QK^T (S^T = mfma(K,Q)),
//          P rebuilt in-register via cvt_pk_bf16 + permlane32_swap (T12),
//          all operands streamed from L2 (per-XCD 256 KB K/V slice, bid&7).
//          4-wave m-split reduced through LDS once; bf16 partials -> ws.
// K3 epi:  sum 8 partials, w_v projection via mfma16, + bias + z residual.
// ---------------------------------------------------------------------------

#define NSEQ 4096
#define CI 128
#define CO 64

typedef __attribute__((ext_vector_type(8))) short bf16x8;   // 8 bf16 = 4 VGPR
typedef __attribute__((ext_vector_type(4))) short bf16x4;   // 4 bf16 = 2 VGPR
typedef __attribute__((ext_vector_type(4))) float f32x4;
typedef __attribute__((ext_vector_type(16))) float f32x16;

static __device__ inline short f2bf(float f) {
  union { float f; unsigned u; } v; v.f = f;
  unsigned r = v.u + 0x7fffu + ((v.u >> 16) & 1u);   // RNE
  return (short)(r >> 16);
}
static __device__ inline float bf2f(short s) {
  union { unsigned u; float f; } v; v.u = ((unsigned)(unsigned short)s) << 16;
  return v.f;
}

#define MFMA1632(a, b, c) __builtin_amdgcn_mfma_f32_16x16x32_bf16(a, b, c, 0, 0, 0)
#define MFMA3216(a, b, c) __builtin_amdgcn_mfma_f32_32x32x16_bf16(a, b, c, 0, 0, 0)

#if __has_builtin(__builtin_amdgcn_mfma_f32_16x16x16bf16_1k)
static __device__ inline f32x4 mfma16(bf16x4 a, bf16x4 b, f32x4 c) {
  return __builtin_amdgcn_mfma_f32_16x16x16bf16_1k(a, b, c, 0, 0, 0);
}
#else
static __device__ inline f32x4 mfma16(bf16x4 a, bf16x4 b, f32x4 c) {
  asm("v_mfma_f32_16x16x16_bf16 %0, %1, %2, %0" : "+v"(c) : "v"(a), "v"(b));
  return c;
}
#endif

static __device__ inline unsigned cvt_pk_bf16(float lo, float hi) {
  unsigned d;
  asm("v_cvt_pk_bf16_f32 %0, %1, %2" : "=v"(d) : "v"(lo), "v"(hi));
  return d;
}
static __device__ inline void pl32swap(unsigned& a, unsigned& b) {
  // new a: lanes32-63 <- old b lanes0-31; new b: lanes0-31 <- old a lanes32-63
  asm("v_permlane32_swap_b32 %0, %1" : "+v"(a), "+v"(b));
}

// ---------------------------------------------------------------------------
// Kernel 1: projections. grid = B * (N/16) = 512 WGs, 256 threads, no LDS.
// phi path pre-scaled by 1/4096 (relu commutes with positive scale).
// ---------------------------------------------------------------------------
__global__ __launch_bounds__(256, 2) void proj_kernel(
    const float* __restrict__ z,
    const float* __restrict__ w_th, const float* __restrict__ b_th,
    const float* __restrict__ w_ph, const float* __restrict__ b_ph,
    const float* __restrict__ w_ps, const float* __restrict__ b_ps,
    short* __restrict__ Qg, short* __restrict__ Kg, short* __restrict__ Vt)
{
  const int bid = blockIdx.x;
  const int b = bid >> 8;
  const int n0 = (bid & 255) * 16;
  const int t = threadIdx.x;
  const int w = t >> 6, l = t & 63, lr = l & 15, lg = l >> 4;
  const f32x4 zero4 = {0.f, 0.f, 0.f, 0.f};

  // zf[ks][j] = z[c = ks*32+lg*8+j][n0+lr]
  bf16x8 zf[4];
#pragma unroll
  for (int ks = 0; ks < 4; ++ks) {
    const float* zp = z + (size_t)(b * CI + ks * 32 + lg * 8) * NSEQ + n0 + lr;
    float tmp[8];
#pragma unroll
    for (int j = 0; j < 8; ++j) tmp[j] = zp[(size_t)j * NSEQ];
#pragma unroll
    for (int j = 0; j < 8; ++j) zf[ks][j] = f2bf(tmp[j]);
  }

  // Q (phi, scaled), K (psi): D[o = w*16 + lg*4 + r][n = n0 + lr]
  {
    const float* Wm[2] = {w_ph, w_ps};
    const float* Bm[2] = {b_ph, b_ps};
    short*       Dm[2] = {Qg, Kg};
#pragma unroll
    for (int mt = 0; mt < 2; ++mt) {
      const float sc = (mt == 0) ? (1.0f / 4096.0f) : 1.0f;
      f32x4 acc = zero4;
#pragma unroll
      for (int ks = 0; ks < 4; ++ks) {
        const float* wp = Wm[mt] + (size_t)(w * 16 + lr) * CI + ks * 32 + lg * 8;
        f32x4 x0 = *(const f32x4*)wp;
        f32x4 x1 = *(const f32x4*)(wp + 4);
        bf16x8 wf;
#pragma unroll
        for (int j = 0; j < 4; ++j) { wf[j] = f2bf(x0[j] * sc); wf[4 + j] = f2bf(x1[j] * sc); }
        acc = MFMA1632(wf, zf[ks], acc);
      }
      const f32x4 bias4 = *(const f32x4*)(Bm[mt] + w * 16 + lg * 4);
      bf16x4 pk;
#pragma unroll
      for (int r = 0; r < 4; ++r) pk[r] = f2bf(acc[r] + bias4[r] * sc);
      *(bf16x4*)(Dm[mt] + (size_t)(b * NSEQ + n0 + lr) * CO + w * 16 + lg * 4) = pk;
    }
  }

  // V (theta^T): D[n = n0 + lg*4 + r][o = w*16 + lr]
  {
    f32x4 acc = zero4;
#pragma unroll
    for (int ks = 0; ks < 4; ++ks) {
      const float* wp = w_th + (size_t)(w * 16 + lr) * CI + ks * 32 + lg * 8;
      f32x4 x0 = *(const f32x4*)wp;
      f32x4 x1 = *(const f32x4*)(wp + 4);
      bf16x8 wtf;
#pragma unroll
      for (int j = 0; j < 4; ++j) { wtf[j] = f2bf(x0[j]); wtf[4 + j] = f2bf(x1[j]); }
      acc = MFMA1632(zf[ks], wtf, acc);
    }
    const float bias = b_th[w * 16 + lr];
    bf16x4 pk;
#pragma unroll
    for (int r = 0; r < 4; ++r) pk[r] = f2bf(acc[r] + bias);
    *(bf16x4*)(Vt + (size_t)(b * CO + w * 16 + lr) * NSEQ + n0 + lg * 4) = pk;
  }
}

// ---------------------------------------------------------------------------
// Kernel 2: fused relu-attention, no-LDS main loop. grid = 1024, 256 thr.
// bid&7 = msplit (XCD-local 512-m K/V slice); bid>>3 -> (b, 64-n tile).
// Wave w owns m-range [ms*512 + w*128, +128), 4 iters of 32 m:
//   S^T[32m][32n] = mfma32x32(K,Q) x2 nsub; relu; cvt_pk+permlane32_swap ->
//   PV B-frags; O^T += mfma32x32(V, P) x (2 kw, 2 osub, 2 nsub).
// Epilogue: 4-wave reduce via 32 KB LDS, bf16 partial -> Opart[b][nt][ms].
// ---------------------------------------------------------------------------
__global__ __launch_bounds__(256, 3) void attn_kernel(
    const short* __restrict__ Qg, const short* __restrict__ Kg,
    const short* __restrict__ Vt, short* __restrict__ Opart)
{
  __shared__ float red[2][4096];         // 32 KB

  const int bid = blockIdx.x;
  const int ms = bid & 7;
  const int rr = bid >> 3;               // 0..127
  const int b  = rr & 1;
  const int nt = rr >> 1;                // 0..63
  const int n0 = nt * 64;
  const int t = threadIdx.x;
  const int w = t >> 6, l = t & 63, lc = l & 31, h = l >> 5;
  const int mw = ms * 512 + w * 128;     // wave's m-base

  // Q B-frags (persistent): qf[nsub][ks]: n = n0+nsub*32+lc, c = ks*16+h*8+j
  bf16x8 qf[2][4];
  {
    const short* qb = Qg + (size_t)(b * NSEQ + n0 + lc) * CO + h * 8;
#pragma unroll
    for (int nsub = 0; nsub < 2; ++nsub)
#pragma unroll
      for (int ks = 0; ks < 4; ++ks)
        qf[nsub][ks] = *(const bf16x8*)(qb + (size_t)nsub * 32 * CO + ks * 16);
  }

  f32x16 oacc[2][2];                     // [osub][nsub]
#pragma unroll
  for (int i = 0; i < 2; ++i)
#pragma unroll
    for (int j = 0; j < 2; ++j)
#pragma unroll
      for (int e = 0; e < 16; ++e) oacc[i][j][e] = 0.f;

#pragma unroll
  for (int it = 0; it < 4; ++it) {
    const int m0 = mw + it * 32;

    // K A-frags: row m = m0+lc, k(c) = ks*16 + h*8 + j
    bf16x8 kf[4];
    {
      const short* kb = Kg + (size_t)(b * NSEQ + m0 + lc) * CO + h * 8;
#pragma unroll
      for (int ks = 0; ks < 4; ++ks) kf[ks] = *(const bf16x8*)(kb + ks * 16);
    }

    // S^T tiles: D row m_local=(reg&3)+8*(reg>>2)+4h, col n=lc
    f32x16 s0, s1;
#pragma unroll
    for (int e = 0; e < 16; ++e) { s0[e] = 0.f; s1[e] = 0.f; }
#pragma unroll
    for (int ks = 0; ks < 4; ++ks) s0 = MFMA3216(kf[ks], qf[0][ks], s0);
    unsigned pk0[8];
#pragma unroll
    for (int q = 0; q < 8; ++q)
      pk0[q] = cvt_pk_bf16(fmaxf(s0[2 * q], 0.f), fmaxf(s0[2 * q + 1], 0.f));
#pragma unroll
    for (int ks = 0; ks < 4; ++ks) s1 = MFMA3216(kf[ks], qf[1][ks], s1);
    unsigned pk1[8];
#pragma unroll
    for (int q = 0; q < 8; ++q)
      pk1[q] = cvt_pk_bf16(fmaxf(s1[2 * q], 0.f), fmaxf(s1[2 * q + 1], 0.f));

    // PV: per kw (16-m window) rebuild B-frags and accumulate
    const short* vb = Vt + (size_t)(b * CO + lc) * NSEQ + m0 + h * 8;
#pragma unroll
    for (int kw = 0; kw < 2; ++kw) {
      unsigned x0 = pk0[4 * kw + 0], y0 = pk0[4 * kw + 2];
      unsigned x1 = pk0[4 * kw + 1], y1 = pk0[4 * kw + 3];
      pl32swap(x0, y0); pl32swap(x1, y1);
      union { unsigned u[4]; bf16x8 v; } pb0 = {{x0, x1, y0, y1}};
      unsigned u0 = pk1[4 * kw + 0], v0 = pk1[4 * kw + 2];
      unsigned u1 = pk1[4 * kw + 1], v1 = pk1[4 * kw + 3];
      pl32swap(u0, v0); pl32swap(u1, v1);
      union { unsigned u[4]; bf16x8 v; } pb1 = {{u0, u1, v0, v1}};

      bf16x8 vf0 = *(const bf16x8*)(vb + kw * 16);
      bf16x8 vf1 = *(const bf16x8*)(vb + (size_t)32 * NSEQ + kw * 16);
      oacc[0][0] = MFMA3216(vf0, pb0.v, oacc[0][0]);
      oacc[1][0] = MFMA3216(vf1, pb0.v, oacc[1][0]);
      oacc[0][1] = MFMA3216(vf0, pb1.v, oacc[0][1]);
      oacc[1][1] = MFMA3216(vf1, pb1.v, oacc[1][1]);
    }
  }

  // ---- 4-wave reduce: pairs (0,1)->red[0], (2,3)->red[1], swizzled [n][o] ----
  // oacc[osub][nsub][reg] = O^T[o = osub*32+(reg&3)+8*(reg>>2)+4h][n = nsub*32+lc]
  if (!(w & 1)) {
#pragma unroll
    for (int osub = 0; osub < 2; ++osub)
#pragma unroll
      for (int nsub = 0; nsub < 2; ++nsub)
#pragma unroll
        for (int rb = 0; rb < 4; ++rb) {
          f32x4 v;
#pragma unroll
          for (int r = 0; r < 4; ++r) v[r] = oacc[osub][nsub][rb * 4 + r];
          const int o = osub * 32 + rb * 8 + h * 4;
          const int n = nsub * 32 + lc;
          const int os = o ^ ((n & 15) << 2);
          *(f32x4*)&red[w >> 1][n * 64 + os] = v;
        }
  }
  __syncthreads();
  if (w & 1) {
#pragma unroll
    for (int osub = 0; osub < 2; ++osub)
#pragma unroll
      for (int nsub = 0; nsub < 2; ++nsub)
#pragma unroll
        for (int rb = 0; rb < 4; ++rb) {
          const int o = osub * 32 + rb * 8 + h * 4;
          const int n = nsub * 32 + lc;
          const int os = o ^ ((n & 15) << 2);
          float* p = &red[w >> 1][n * 64 + os];
          f32x4 v = *(f32x4*)p;
#pragma unroll
          for (int r = 0; r < 4; ++r) v[r] += oacc[osub][nsub][rb * 4 + r];
          *(f32x4*)p = v;
        }
  }
  __syncthreads();

  // ---- sum halves, un-swizzle, bf16-pack -> Opart slot [n 64][o 64] ----
  short* gout = Opart + (size_t)((b * 64 + nt) * 8 + ms) * 4096;
#pragma unroll
  for (int pass = 0; pass < 4; ++pass) {
    const int lin = pass * 1024 + t * 4;
    const int n = lin >> 6, os4 = lin & 63;
    f32x4 v0 = *(f32x4*)&red[0][lin];
    f32x4 v1 = *(f32x4*)&red[1][lin];
    const int o = os4 ^ ((n & 15) << 2);
    bf16x4 pkv;
#pragma unroll
    for (int r = 0; r < 4; ++r) pkv[r] = f2bf(v0[r] + v1[r]);
    *(bf16x4*)(gout + n * 64 + o) = pkv;
  }
}

// ---------------------------------------------------------------------------
// Kernel 3: sum 8 msplit partials, project with w_v (mfma16), + bias + z.
// grid = B * (N/32) = 256 WGs, 256 threads. Tile = 32 n (half an Opart slot).
// ---------------------------------------------------------------------------
__global__ __launch_bounds__(256, 2) void epi_kernel(
    const short* __restrict__ Opart, const float* __restrict__ w_v,
    const float* __restrict__ b_v, const float* __restrict__ z,
    float* __restrict__ out)
{
  __shared__ float Olds[32 * 65];        // [32 n][64 o] padded, 8.125 KB

  const int bid = blockIdx.x;
  const int b = bid >> 7;
  const int nt32 = bid & 127;
  const int nt = nt32 >> 1, nh2 = nt32 & 1;
  const int t = threadIdx.x;

  // sum 8 partial slots (bf16 [n][o]) -> f32 LDS
  {
    const short* src = Opart + (size_t)((b * 64 + nt) * 8) * 4096 + nh2 * 32 * 64;
    const int n = t >> 3, o8 = (t & 7) * 8;
    float acc[8];
#pragma unroll
    for (int j = 0; j < 8; ++j) acc[j] = 0.f;
#pragma unroll
    for (int p = 0; p < 8; ++p) {
      bf16x8 vv = *(const bf16x8*)(src + (size_t)p * 4096 + n * 64 + o8);
#pragma unroll
      for (int j = 0; j < 8; ++j) acc[j] += bf2f(vv[j]);
    }
#pragma unroll
    for (int j = 0; j < 8; ++j) Olds[n * 65 + o8 + j] = acc[j];
  }
  __syncthreads();

  const int w = t >> 6, l = t & 63, lr = l & 15, lg = l >> 4;
  const f32x4 zero4 = {0.f, 0.f, 0.f, 0.f};

  // O^T B-frags: of[nh][osub][j] = O[o = osub*16+lg*4+j][n = nh*16+lr]
  bf16x4 of[2][4];
#pragma unroll
  for (int nh = 0; nh < 2; ++nh)
#pragma unroll
    for (int osub = 0; osub < 4; ++osub)
#pragma unroll
      for (int j = 0; j < 4; ++j)
        of[nh][osub][j] = f2bf(Olds[(nh * 16 + lr) * 65 + osub * 16 + lg * 4 + j]);

  // wave w -> ci groups {2w, 2w+1}
#pragma unroll
  for (int c2 = 0; c2 < 2; ++c2) {
    const int cis = w * 2 + c2;
    bf16x4 wfr[4];
#pragma unroll
    for (int osub = 0; osub < 4; ++osub) {
      f32x4 wl = *(const f32x4*)(w_v + (size_t)(cis * 16 + lr) * CO + osub * 16 + lg * 4);
#pragma unroll
      for (int j = 0; j < 4; ++j) wfr[osub][j] = f2bf(wl[j]);
    }
    const f32x4 bv4 = *(const f32x4*)(b_v + cis * 16 + lg * 4);
#pragma unroll
    for (int nh = 0; nh < 2; ++nh) {
      f32x4 e = zero4;
#pragma unroll
      for (int osub = 0; osub < 4; ++osub)
        e = mfma16(wfr[osub], of[nh][osub], e);
#pragma unroll
      for (int r = 0; r < 4; ++r) {
        const int ci = cis * 16 + lg * 4 + r;
        const size_t off = (size_t)(b * CI + ci) * NSEQ + nt32 * 32 + nh * 16 + lr;
        out[off] = e[r] + z[off] + bv4[r];
      }
    }
  }
}

// ---------------------------------------------------------------------------
extern "C" void kernel_launch(void* const* d_in, const int* in_sizes, int n_in,
                              void* d_out, int out_size, void* d_ws, size_t ws_size,
                              hipStream_t stream) {
  const float* z    = (const float*)d_in[0];
  const float* w_th = (const float*)d_in[1];
  const float* b_th = (const float*)d_in[2];
  const float* w_ph = (const float*)d_in[3];
  const float* b_ph = (const float*)d_in[4];
  const float* w_ps = (const float*)d_in[5];
  const float* b_ps = (const float*)d_in[6];
  const float* w_v  = (const float*)d_in[7];
  const float* b_v  = (const float*)d_in[8];
  float* out = (float*)d_out;

  short* Qg = (short*)d_ws;                         // [2][4096][64] bf16 = 1 MB
  short* Kg = Qg + 2 * NSEQ * CO;                   // [2][4096][64] bf16 = 1 MB
  short* Vt = Kg + 2 * NSEQ * CO;                   // [2][64][4096] bf16 = 1 MB
  short* Opart = Vt + 2 * NSEQ * CO;                // [2][64][8][64n][64o] bf16 = 8 MB

  proj_kernel<<<512, 256, 0, stream>>>(z, w_th, b_th, w_ph, b_ph, w_ps, b_ps,
                                       Qg, Kg, Vt);
  attn_kernel<<<1024, 256, 0, stream>>>(Qg, Kg, Vt, Opart);
  epi_kernel<<<256, 256, 0, stream>>>(Opart, w_v, b_v, z, out);
}